// Round 3
// baseline (253.986 us; speedup 1.0000x reference)
//
#include <hip/hip_runtime.h>
#include <hip/hip_bf16.h>

#define NWAVES 8192
#define NTRANS 8192
#define NTGT   4096
#define DMODEL 256
#define TOPK   3

// ---------------- Kernel 1: fused gumbel-softmax + top-3 (one block per row) ----------------
template<int NCOLS>
__global__ __launch_bounds__(256)
void topk_softmax_kernel(const float* __restrict__ adj,
                         const float* __restrict__ gum,
                         const float* __restrict__ temp,
                         float* __restrict__ out_src,
                         float* __restrict__ out_tgt,
                         int* __restrict__ ws_idx,
                         float* __restrict__ ws_val)
{
    const int row = blockIdx.x;
    const int tid = threadIdx.x;
    const float inv_tau = 1.0f / temp[0];
    const float* ar = adj + (size_t)row * NCOLS;
    const float* gr = gum + (size_t)row * NCOLS;

    // thread-local top-3 (desc) + online logsumexp state
    float v0 = -INFINITY, v1 = -INFINITY, v2 = -INFINITY;
    int   i0 = 0, i1 = 0, i2 = 0;
    float m = -INFINITY, s = 0.0f;

    for (int base = tid * 4; base < NCOLS; base += 1024) {
        const float4 a4 = *reinterpret_cast<const float4*>(ar + base);
        const float4 g4 = *reinterpret_cast<const float4*>(gr + base);
        float z[4] = { (a4.x + g4.x) * inv_tau, (a4.y + g4.y) * inv_tau,
                       (a4.z + g4.z) * inv_tau, (a4.w + g4.w) * inv_tau };
#pragma unroll
        for (int j = 0; j < 4; ++j) {
            const float zv = z[j];
            const int c = base + j;
            if (zv > m) { s = s * __expf(m - zv) + 1.0f; m = zv; }
            else        { s += __expf(zv - m); }
            if (zv > v2) {  // strict > keeps earliest index on ties (columns ascend per thread)
                if (zv > v0)      { v2=v1; i2=i1; v1=v0; i1=i0; v0=zv; i0=c; }
                else if (zv > v1) { v2=v1; i2=i1; v1=zv; i1=c; }
                else              { v2=zv; i2=c; }
            }
        }
    }

    __shared__ float sv[256][3];
    __shared__ int   si[256][3];
    __shared__ float sm[256];
    __shared__ float ss[256];
    sv[tid][0]=v0; sv[tid][1]=v1; sv[tid][2]=v2;
    si[tid][0]=i0; si[tid][1]=i1; si[tid][2]=i2;
    sm[tid]=m; ss[tid]=s;
    __syncthreads();

    for (int stride = 128; stride >= 1; stride >>= 1) {
        if (tid < stride) {
            const int o = tid + stride;
            float av[3] = {sv[tid][0], sv[tid][1], sv[tid][2]};
            int   ai[3] = {si[tid][0], si[tid][1], si[tid][2]};
            float bv[3] = {sv[o][0], sv[o][1], sv[o][2]};
            int   bi[3] = {si[o][0], si[o][1], si[o][2]};
            float rv[3]; int ri[3];
            int pa = 0, pb = 0;
#pragma unroll
            for (int q = 0; q < 3; ++q) {
                bool takeA;
                if (pb >= 3) takeA = true;
                else takeA = (av[pa] > bv[pb]) || (av[pa] == bv[pb] && ai[pa] < bi[pb]);
                if (takeA) { rv[q]=av[pa]; ri[q]=ai[pa]; ++pa; }
                else       { rv[q]=bv[pb]; ri[q]=bi[pb]; ++pb; }
            }
            sv[tid][0]=rv[0]; sv[tid][1]=rv[1]; sv[tid][2]=rv[2];
            si[tid][0]=ri[0]; si[tid][1]=ri[1]; si[tid][2]=ri[2];
            const float m1 = sm[tid], m2 = sm[o];
            const float M = fmaxf(m1, m2);
            ss[tid] = ss[tid]*__expf(m1 - M) + ss[o]*__expf(m2 - M);
            sm[tid] = M;
        }
        __syncthreads();
    }

    if (tid < TOPK) {
        const float M = sm[0], S = ss[0];
        const float p = __expf(sv[0][tid] - M) / S;
        const int idx = si[0][tid];
        const size_t e = (size_t)row * TOPK + tid;
        out_src[e] = (float)row;
        out_tgt[e] = (float)idx;
        ws_idx[e] = idx;
        ws_val[e] = p;
    }
}

// ---------------- Kernel 2 (path A): f32 GEMM  C[M,256] = A[M,256] @ B[256,256] ----------------
__global__ __launch_bounds__(256)
void gemm_f32_kernel(const float* __restrict__ A, const float* __restrict__ B,
                     float* __restrict__ C, int M)
{
    __shared__ float As[32][68];   // [k][m]; row stride 272B -> float4-aligned
    __shared__ float Bs[32][64];   // [k][n]
    const int tid = threadIdx.x;
    const int tx = tid % 16, ty = tid / 16;
    const int m0 = blockIdx.x * 64;
    const int n0 = blockIdx.y * 64;
    const int lc = tid % 32;       // k (A load)
    const int lr = tid / 32;       // m base (A load)
    const int bn = tid % 64;       // n (B load)
    const int bk = tid / 64;       // k base (B load)
    float acc[4][4] = {};

    for (int k0 = 0; k0 < DMODEL; k0 += 32) {
#pragma unroll
        for (int i = 0; i < 8; ++i) {
            const int r = lr + i * 8;
            As[lc][r] = A[(size_t)(m0 + r) * DMODEL + k0 + lc];
        }
#pragma unroll
        for (int i = 0; i < 8; ++i) {
            const int kk = bk + i * 4;
            Bs[kk][bn] = B[(size_t)(k0 + kk) * DMODEL + n0 + bn];
        }
        __syncthreads();
#pragma unroll
        for (int kk = 0; kk < 32; ++kk) {
            const float4 a4 = *reinterpret_cast<const float4*>(&As[kk][ty * 4]);
            const float4 b4 = *reinterpret_cast<const float4*>(&Bs[kk][tx * 4]);
            const float av[4] = {a4.x, a4.y, a4.z, a4.w};
            const float bv[4] = {b4.x, b4.y, b4.z, b4.w};
#pragma unroll
            for (int i = 0; i < 4; ++i)
#pragma unroll
                for (int j = 0; j < 4; ++j)
                    acc[i][j] += av[i] * bv[j];
        }
        __syncthreads();
    }
#pragma unroll
    for (int i = 0; i < 4; ++i) {
        float4 c4 = {acc[i][0], acc[i][1], acc[i][2], acc[i][3]};
        *reinterpret_cast<float4*>(&C[(size_t)(m0 + ty * 4 + i) * DMODEL + n0 + tx * 4]) = c4;
    }
}

// ---------------- Kernel 3 (path A): per-edge weight from precomputed halves ----------------
__global__ __launch_bounds__(256)
void edge_weight_kernel(const float* __restrict__ Arows,
                        const float* __restrict__ Brows,
                        const int* __restrict__ eidx,
                        const float* __restrict__ evals,
                        const float* __restrict__ b1,
                        const float* __restrict__ w2,
                        const float* __restrict__ b2,
                        float* __restrict__ out_w,
                        int nEdges)
{
    const int lane = threadIdx.x & 63;
    const int wv   = threadIdx.x >> 6;
    const int e = blockIdx.x * 4 + wv;
    if (e >= nEdges) return;
    const int srow = e / 3;
    const int trow = eidx[e];
    const float4 a4 = *reinterpret_cast<const float4*>(Arows + (size_t)srow * DMODEL + lane * 4);
    const float4 b4 = *reinterpret_cast<const float4*>(Brows + (size_t)trow * DMODEL + lane * 4);
    const float4 c4 = *reinterpret_cast<const float4*>(b1 + lane * 4);
    const float4 w4 = *reinterpret_cast<const float4*>(w2 + lane * 4);
    float acc = fmaxf(a4.x + b4.x + c4.x, 0.f) * w4.x
              + fmaxf(a4.y + b4.y + c4.y, 0.f) * w4.y
              + fmaxf(a4.z + b4.z + c4.z, 0.f) * w4.z
              + fmaxf(a4.w + b4.w + c4.w, 0.f) * w4.w;
#pragma unroll
    for (int off = 32; off >= 1; off >>= 1) acc += __shfl_xor(acc, off);
    if (lane == 0) {
        const float x = acc + b2[0];
        const float sig = 1.0f / (1.0f + __expf(-x));
        out_w[e] = sig * evals[e];
    }
}

// ---------------- Kernel 4 (path B fallback): direct per-edge MLP, 16 edges/block ----------------
__global__ __launch_bounds__(256)
void edge_mlp_direct_kernel(const float* __restrict__ src_feat,
                            const float* __restrict__ tgt_feat,
                            const int* __restrict__ eidx,
                            const float* __restrict__ evals,
                            const float* __restrict__ w1,
                            const float* __restrict__ b1,
                            const float* __restrict__ w2,
                            const float* __restrict__ b2,
                            float* __restrict__ out_w,
                            int nEdges)
{
    __shared__ float E[512][16];
    __shared__ float part[16][4];
    const int tid = threadIdx.x;
    const int e0 = blockIdx.x * 16;

    for (int i = tid; i < 16 * 128; i += 256) {
        const int e = i >> 7;
        const int q = i & 127;
        const int eg = e0 + e;
        float4 v;
        if (eg < nEdges) {
            if (q < 64) {
                const float* r = src_feat + (size_t)(eg / 3) * DMODEL;
                v = *reinterpret_cast<const float4*>(r + q * 4);
            } else {
                const float* r = tgt_feat + (size_t)eidx[eg] * DMODEL;
                v = *reinterpret_cast<const float4*>(r + (q - 64) * 4);
            }
        } else {
            v = make_float4(0.f, 0.f, 0.f, 0.f);
        }
        const int k = q * 4;
        E[k + 0][e] = v.x; E[k + 1][e] = v.y; E[k + 2][e] = v.z; E[k + 3][e] = v.w;
    }
    __syncthreads();

    const int j = tid;
    float acc[16];
#pragma unroll
    for (int e = 0; e < 16; ++e) acc[e] = 0.f;

    for (int k = 0; k < 512; ++k) {
        const float w = w1[(size_t)k * DMODEL + j];
        const float4 a = *reinterpret_cast<const float4*>(&E[k][0]);
        const float4 b = *reinterpret_cast<const float4*>(&E[k][4]);
        const float4 c = *reinterpret_cast<const float4*>(&E[k][8]);
        const float4 d = *reinterpret_cast<const float4*>(&E[k][12]);
        acc[0] += a.x * w;  acc[1] += a.y * w;  acc[2] += a.z * w;  acc[3] += a.w * w;
        acc[4] += b.x * w;  acc[5] += b.y * w;  acc[6] += b.z * w;  acc[7] += b.w * w;
        acc[8] += c.x * w;  acc[9] += c.y * w;  acc[10] += c.z * w; acc[11] += c.w * w;
        acc[12] += d.x * w; acc[13] += d.y * w; acc[14] += d.z * w; acc[15] += d.w * w;
    }

    const float b1j = b1[j];
    const float w2j = w2[j];
    const int lane = tid & 63;
    const int wv = tid >> 6;
#pragma unroll
    for (int e = 0; e < 16; ++e) {
        float v = fmaxf(acc[e] + b1j, 0.f) * w2j;
#pragma unroll
        for (int off = 32; off >= 1; off >>= 1) v += __shfl_xor(v, off);
        if (lane == 0) part[e][wv] = v;
    }
    __syncthreads();
    if (tid < 16) {
        const int eg = e0 + tid;
        if (eg < nEdges) {
            const float x = part[tid][0] + part[tid][1] + part[tid][2] + part[tid][3] + b2[0];
            const float sig = 1.0f / (1.0f + __expf(-x));
            out_w[eg] = sig * evals[eg];
        }
    }
}

extern "C" void kernel_launch(void* const* d_in, const int* in_sizes, int n_in,
                              void* d_out, int out_size, void* d_ws, size_t ws_size,
                              hipStream_t stream)
{
    const float* wave   = (const float*)d_in[0];   // [4, 8192, 256] (batch 0 = first slab)
    const float* trans  = (const float*)d_in[1];   // [4, 8192, 256]
    const float* target = (const float*)d_in[2];   // [4, 4096, 256]
    const float* w2t    = (const float*)d_in[3];   // [8192, 8192]
    const float* t2t    = (const float*)d_in[4];   // [8192, 4096]
    const float* temp   = (const float*)d_in[5];   // scalar
    const float* g_wt   = (const float*)d_in[6];   // [8192, 8192]
    const float* g_tt   = (const float*)d_in[7];   // [8192, 4096]
    const float* wt_w1  = (const float*)d_in[8];   // [512, 256]
    const float* wt_b1  = (const float*)d_in[9];   // [256]
    const float* wt_w2  = (const float*)d_in[10];  // [256]
    const float* wt_b2  = (const float*)d_in[11];  // [1]
    const float* tt_w1  = (const float*)d_in[12];
    const float* tt_b1  = (const float*)d_in[13];
    const float* tt_w2  = (const float*)d_in[14];
    const float* tt_b2  = (const float*)d_in[15];

    float* out = (float*)d_out;     // FLOAT32 output (edges are int-valued floats)
    const int EW = NWAVES * TOPK;   // 24576
    const int ET = NTRANS * TOPK;   // 24576
    float* wt_src = out;
    float* wt_tgt = out + EW;
    float* wt_wgt = out + 2 * EW;
    float* tt_src = out + 3 * EW;
    float* tt_tgt = out + 3 * EW + ET;
    float* tt_wgt = out + 3 * EW + 2 * ET;

    // ---- workspace budgeting ----
    const size_t nodeFloats = (size_t)(NWAVES + NTRANS + NTRANS + NTGT) * DMODEL; // 7,340,032
    const size_t edgeFloats = (size_t)(EW + ET);                                  // 49,152
    const size_t needBig   = (nodeFloats + 2 * edgeFloats) * sizeof(float) + 2 * edgeFloats * sizeof(int);
    const bool   bigPath   = (ws_size >= needBig);

    float *AW = nullptr, *BW = nullptr, *AT = nullptr, *BT = nullptr;
    float *wt_val, *tt_val; int *wt_idx, *tt_idx;
    if (bigPath) {
        AW = (float*)d_ws;
        BW = AW + NWAVES * DMODEL;
        AT = BW + NTRANS * DMODEL;
        BT = AT + NTRANS * DMODEL;
        wt_val = BT + NTGT * DMODEL;
        tt_val = wt_val + EW;
        wt_idx = (int*)(tt_val + ET);
        tt_idx = wt_idx + EW;
    } else {
        wt_val = (float*)d_ws;
        tt_val = wt_val + EW;
        wt_idx = (int*)(tt_val + ET);
        tt_idx = wt_idx + EW;
    }

    // 1) streaming gumbel-softmax top-3
    topk_softmax_kernel<NTRANS><<<NWAVES, 256, 0, stream>>>(w2t, g_wt, temp, wt_src, wt_tgt, wt_idx, wt_val);
    topk_softmax_kernel<NTGT><<<NTRANS, 256, 0, stream>>>(t2t, g_tt, temp, tt_src, tt_tgt, tt_idx, tt_val);

    if (bigPath) {
        // 2) per-node MLP first-layer halves
        gemm_f32_kernel<<<dim3(NWAVES / 64, DMODEL / 64), 256, 0, stream>>>(wave,   wt_w1,                   AW, NWAVES);
        gemm_f32_kernel<<<dim3(NTRANS / 64, DMODEL / 64), 256, 0, stream>>>(trans,  wt_w1 + DMODEL * DMODEL, BW, NTRANS);
        gemm_f32_kernel<<<dim3(NTRANS / 64, DMODEL / 64), 256, 0, stream>>>(trans,  tt_w1,                   AT, NTRANS);
        gemm_f32_kernel<<<dim3(NTGT  / 64, DMODEL / 64), 256, 0, stream>>>(target, tt_w1 + DMODEL * DMODEL, BT, NTGT);
        // 3) per-edge weight
        edge_weight_kernel<<<(EW + 3) / 4, 256, 0, stream>>>(AW, BW, wt_idx, wt_val, wt_b1, wt_w2, wt_b2, wt_wgt, EW);
        edge_weight_kernel<<<(ET + 3) / 4, 256, 0, stream>>>(AT, BT, tt_idx, tt_val, tt_b1, tt_w2, tt_b2, tt_wgt, ET);
    } else {
        edge_mlp_direct_kernel<<<(EW + 15) / 16, 256, 0, stream>>>(wave,  trans,  wt_idx, wt_val, wt_w1, wt_b1, wt_w2, wt_b2, wt_wgt, EW);
        edge_mlp_direct_kernel<<<(ET + 15) / 16, 256, 0, stream>>>(trans, target, tt_idx, tt_val, tt_w1, tt_b1, tt_w2, tt_b2, tt_wgt, ET);
    }
}

// Round 4
// 216.244 us; speedup vs baseline: 1.1745x; 1.1745x over previous
//
#include <hip/hip_runtime.h>

#define NWAVES 8192
#define NTRANS 8192
#define NTGT   4096
#define DMODEL 256
#define TOPK   3
#define EW (NWAVES * TOPK)   // 24576
#define ET (NTRANS * TOPK)   // 24576

struct TopkLds {
    float sv[256][3];
    int   si[256][3];
    float ss[256];
};
struct GemmLds {
    float As[32][68];   // [k][m]; stride 68 floats -> float4-aligned rows, conflict-free
    float Bs[32][64];   // [k][n]
};
// GemmLds (16896B) > TopkLds (7168B): shared buffer sized for GemmLds.

// ---------------- topk body: streaming gumbel-softmax + branchless top-3 ----------------
template<int NCOLS>
__device__ __forceinline__ void topk_body(void* ldsraw, int row,
        const float* __restrict__ adj, const float* __restrict__ gum,
        float inv_tau,
        float* __restrict__ out_src, float* __restrict__ out_tgt,
        int* __restrict__ ws_idx, float* __restrict__ ws_val)
{
    TopkLds& L = *reinterpret_cast<TopkLds*>(ldsraw);
    const int tid = threadIdx.x;
    const float* ar = adj + (size_t)row * NCOLS;
    const float* gr = gum + (size_t)row * NCOLS;

    // z' = (a+g)*inv_tau - 10  (safe range for direct exp sum; same argsort as softmax)
    float v0 = -1e30f, v1 = -1e30f, v2 = -1e30f;
    int   i0 = 0, i1 = 0, i2 = 0;
    float s0 = 0.f, s1 = 0.f, s2 = 0.f, s3 = 0.f;

    auto upd3 = [&](float z, int c) {
        const bool gt0 = z > v0, gt1 = z > v1, gt2 = z > v2;
        v2 = gt1 ? v1 : fmaxf(z, v2);  i2 = gt1 ? i1 : (gt2 ? c : i2);
        v1 = gt0 ? v0 : fmaxf(z, v1);  i1 = gt0 ? i0 : (gt1 ? c : i1);
        v0 = fmaxf(z, v0);             i0 = gt0 ? c  : i0;
    };

#pragma unroll
    for (int base = 0; base < NCOLS; base += 1024) {
        const int c0 = base + tid * 4;
        const float4 a4 = *reinterpret_cast<const float4*>(ar + c0);
        const float4 g4 = *reinterpret_cast<const float4*>(gr + c0);
        const float za = fmaf(a4.x + g4.x, inv_tau, -10.0f);
        const float zb = fmaf(a4.y + g4.y, inv_tau, -10.0f);
        const float zc = fmaf(a4.z + g4.z, inv_tau, -10.0f);
        const float zd = fmaf(a4.w + g4.w, inv_tau, -10.0f);
        s0 += __expf(za); s1 += __expf(zb); s2 += __expf(zc); s3 += __expf(zd);
        upd3(za, c0); upd3(zb, c0 + 1); upd3(zc, c0 + 2); upd3(zd, c0 + 3);
    }

    L.sv[tid][0] = v0; L.sv[tid][1] = v1; L.sv[tid][2] = v2;
    L.si[tid][0] = i0; L.si[tid][1] = i1; L.si[tid][2] = i2;
    L.ss[tid] = (s0 + s1) + (s2 + s3);
    __syncthreads();

    for (int stride = 128; stride >= 1; stride >>= 1) {
        if (tid < stride) {
            const int o = tid + stride;
            float av[3] = {L.sv[tid][0], L.sv[tid][1], L.sv[tid][2]};
            int   ai[3] = {L.si[tid][0], L.si[tid][1], L.si[tid][2]};
            float bv[3] = {L.sv[o][0], L.sv[o][1], L.sv[o][2]};
            int   bi[3] = {L.si[o][0], L.si[o][1], L.si[o][2]};
            float rv[3]; int ri[3];
            int pa = 0, pb = 0;
#pragma unroll
            for (int q = 0; q < 3; ++q) {
                bool takeA;
                if (pb >= 3) takeA = true;
                else takeA = (av[pa] > bv[pb]) || (av[pa] == bv[pb] && ai[pa] < bi[pb]);
                if (takeA) { rv[q] = av[pa]; ri[q] = ai[pa]; ++pa; }
                else       { rv[q] = bv[pb]; ri[q] = bi[pb]; ++pb; }
            }
            L.sv[tid][0] = rv[0]; L.sv[tid][1] = rv[1]; L.sv[tid][2] = rv[2];
            L.si[tid][0] = ri[0]; L.si[tid][1] = ri[1]; L.si[tid][2] = ri[2];
            L.ss[tid] += L.ss[o];
        }
        __syncthreads();
    }

    if (tid < TOPK) {
        const float S = L.ss[0];
        const float p = __expf(L.sv[0][tid]) / S;
        const int idx = L.si[0][tid];
        const size_t e = (size_t)row * TOPK + tid;
        out_src[e] = (float)row;
        out_tgt[e] = (float)idx;
        ws_idx[e] = idx;
        ws_val[e] = p;
    }
}

// ---------------- gemm body: C[64x64 tile] = A[M,256] @ B[256,256] ----------------
__device__ __forceinline__ void gemm_body(void* ldsraw,
        const float* __restrict__ A, const float* __restrict__ B,
        float* __restrict__ C, int m0, int n0)
{
    GemmLds& L = *reinterpret_cast<GemmLds*>(ldsraw);
    const int tid = threadIdx.x;
    const int tx = tid % 16, ty = tid / 16;
    const int lc = tid % 32;       // k (A load)
    const int lr = tid / 32;       // m base (A load)
    const int bn = tid % 64;       // n (B load)
    const int bk = tid / 64;       // k base (B load)
    float acc[4][4] = {};

    for (int k0 = 0; k0 < DMODEL; k0 += 32) {
#pragma unroll
        for (int i = 0; i < 8; ++i) {
            const int r = lr + i * 8;
            L.As[lc][r] = A[(size_t)(m0 + r) * DMODEL + k0 + lc];
        }
#pragma unroll
        for (int i = 0; i < 8; ++i) {
            const int kk = bk + i * 4;
            L.Bs[kk][bn] = B[(size_t)(k0 + kk) * DMODEL + n0 + bn];
        }
        __syncthreads();
#pragma unroll
        for (int kk = 0; kk < 32; ++kk) {
            const float4 a4 = *reinterpret_cast<const float4*>(&L.As[kk][ty * 4]);
            const float4 b4 = *reinterpret_cast<const float4*>(&L.Bs[kk][tx * 4]);
            const float av[4] = {a4.x, a4.y, a4.z, a4.w};
            const float bv[4] = {b4.x, b4.y, b4.z, b4.w};
#pragma unroll
            for (int i = 0; i < 4; ++i)
#pragma unroll
                for (int j = 0; j < 4; ++j)
                    acc[i][j] += av[i] * bv[j];
        }
        __syncthreads();
    }
#pragma unroll
    for (int i = 0; i < 4; ++i) {
        float4 c4 = {acc[i][0], acc[i][1], acc[i][2], acc[i][3]};
        *reinterpret_cast<float4*>(&C[(size_t)(m0 + ty * 4 + i) * DMODEL + n0 + tx * 4]) = c4;
    }
}

// ---------------- fused main: topk blocks + interleaved gemm blocks ----------------
__global__ __launch_bounds__(256)
void fused_main_kernel(const float* __restrict__ w2t, const float* __restrict__ g_wt,
                       const float* __restrict__ t2t, const float* __restrict__ g_tt,
                       const float* __restrict__ temp,
                       const float* __restrict__ wave, const float* __restrict__ trans,
                       const float* __restrict__ target,
                       const float* __restrict__ wt_w1, const float* __restrict__ tt_w1,
                       float* wt_src, float* wt_tgt, int* wt_idx, float* wt_val,
                       float* tt_src, float* tt_tgt, int* tt_idx, float* tt_val,
                       float* AW, float* BW, float* AT, float* BT,
                       int nGemm)
{
    __shared__ alignas(16) unsigned char ldsraw[sizeof(GemmLds)];
    const int bid = blockIdx.x;

    int topk_id, gemm_id = -1;
    if (nGemm > 0) {
        const int inter = nGemm * 10;
        if (bid < inter) {
            if (bid % 10 == 0) gemm_id = bid / 10;
            else topk_id = bid - bid / 10 - 1;
        } else {
            topk_id = bid - nGemm;
        }
    } else {
        topk_id = bid;
    }

    if (gemm_id >= 0) {
        const float* A; const float* B; float* C; int mblk, nblk;
        if (gemm_id < 512)       { A = wave;   B = wt_w1;                   C = AW; int g = gemm_id;        mblk = g % 128; nblk = g / 128; }
        else if (gemm_id < 1024) { A = trans;  B = wt_w1 + DMODEL * DMODEL; C = BW; int g = gemm_id - 512;  mblk = g % 128; nblk = g / 128; }
        else if (gemm_id < 1536) { A = trans;  B = tt_w1;                   C = AT; int g = gemm_id - 1024; mblk = g % 128; nblk = g / 128; }
        else                     { A = target; B = tt_w1 + DMODEL * DMODEL; C = BT; int g = gemm_id - 1536; mblk = g % 64;  nblk = g / 64;  }
        gemm_body(ldsraw, A, B, C, mblk * 64, nblk * 64);
        return;
    }

    const float inv_tau = 1.0f / temp[0];
    if (topk_id < NWAVES)
        topk_body<NTRANS>(ldsraw, topk_id, w2t, g_wt, inv_tau, wt_src, wt_tgt, wt_idx, wt_val);
    else
        topk_body<NTGT>(ldsraw, topk_id - NWAVES, t2t, g_tt, inv_tau, tt_src, tt_tgt, tt_idx, tt_val);
}

// ---------------- fused per-edge weight (big path) ----------------
__global__ __launch_bounds__(256)
void edge_weight_fused_kernel(const float* __restrict__ AW, const float* __restrict__ BW,
                              const float* __restrict__ AT, const float* __restrict__ BT,
                              const int* __restrict__ wt_idx, const float* __restrict__ wt_val,
                              const int* __restrict__ tt_idx, const float* __restrict__ tt_val,
                              const float* __restrict__ wt_b1, const float* __restrict__ wt_w2, const float* __restrict__ wt_b2,
                              const float* __restrict__ tt_b1, const float* __restrict__ tt_w2, const float* __restrict__ tt_b2,
                              float* __restrict__ wt_out, float* __restrict__ tt_out)
{
    const int lane = threadIdx.x & 63;
    const int wv   = threadIdx.x >> 6;
    const int eg = blockIdx.x * 4 + wv;     // 0 .. EW+ET-1

    const bool isWT = (eg < EW);
    const int e = isWT ? eg : eg - EW;
    const float* Arows = isWT ? AW : AT;
    const float* Brows = isWT ? BW : BT;
    const int*   eidx  = isWT ? wt_idx : tt_idx;
    const float* evals = isWT ? wt_val : tt_val;
    const float* b1    = isWT ? wt_b1 : tt_b1;
    const float* w2    = isWT ? wt_w2 : tt_w2;
    const float* b2    = isWT ? wt_b2 : tt_b2;
    float*       outw  = isWT ? wt_out : tt_out;

    const int srow = e / 3;
    const int trow = eidx[e];
    const float4 a4 = *reinterpret_cast<const float4*>(Arows + (size_t)srow * DMODEL + lane * 4);
    const float4 b4 = *reinterpret_cast<const float4*>(Brows + (size_t)trow * DMODEL + lane * 4);
    const float4 c4 = *reinterpret_cast<const float4*>(b1 + lane * 4);
    const float4 w4 = *reinterpret_cast<const float4*>(w2 + lane * 4);
    float acc = fmaxf(a4.x + b4.x + c4.x, 0.f) * w4.x
              + fmaxf(a4.y + b4.y + c4.y, 0.f) * w4.y
              + fmaxf(a4.z + b4.z + c4.z, 0.f) * w4.z
              + fmaxf(a4.w + b4.w + c4.w, 0.f) * w4.w;
#pragma unroll
    for (int off = 32; off >= 1; off >>= 1) acc += __shfl_xor(acc, off);
    if (lane == 0) {
        const float x = acc + b2[0];
        const float sig = 1.0f / (1.0f + __expf(-x));
        outw[e] = sig * evals[e];
    }
}

// ---------------- fallback: direct per-edge MLP (small ws) ----------------
__global__ __launch_bounds__(256)
void edge_mlp_direct_kernel(const float* __restrict__ src_feat,
                            const float* __restrict__ tgt_feat,
                            const int* __restrict__ eidx,
                            const float* __restrict__ evals,
                            const float* __restrict__ w1,
                            const float* __restrict__ b1,
                            const float* __restrict__ w2,
                            const float* __restrict__ b2,
                            float* __restrict__ out_w,
                            int nEdges)
{
    __shared__ float E[512][16];
    __shared__ float part[16][4];
    const int tid = threadIdx.x;
    const int e0 = blockIdx.x * 16;

    for (int i = tid; i < 16 * 128; i += 256) {
        const int e = i >> 7;
        const int q = i & 127;
        const int eg = e0 + e;
        float4 v;
        if (eg < nEdges) {
            if (q < 64) {
                const float* r = src_feat + (size_t)(eg / 3) * DMODEL;
                v = *reinterpret_cast<const float4*>(r + q * 4);
            } else {
                const float* r = tgt_feat + (size_t)eidx[eg] * DMODEL;
                v = *reinterpret_cast<const float4*>(r + (q - 64) * 4);
            }
        } else {
            v = make_float4(0.f, 0.f, 0.f, 0.f);
        }
        const int k = q * 4;
        E[k + 0][e] = v.x; E[k + 1][e] = v.y; E[k + 2][e] = v.z; E[k + 3][e] = v.w;
    }
    __syncthreads();

    const int j = tid;
    float acc[16];
#pragma unroll
    for (int e = 0; e < 16; ++e) acc[e] = 0.f;

    for (int k = 0; k < 512; ++k) {
        const float w = w1[(size_t)k * DMODEL + j];
        const float4 a = *reinterpret_cast<const float4*>(&E[k][0]);
        const float4 b = *reinterpret_cast<const float4*>(&E[k][4]);
        const float4 c = *reinterpret_cast<const float4*>(&E[k][8]);
        const float4 d = *reinterpret_cast<const float4*>(&E[k][12]);
        acc[0] += a.x * w;  acc[1] += a.y * w;  acc[2] += a.z * w;  acc[3] += a.w * w;
        acc[4] += b.x * w;  acc[5] += b.y * w;  acc[6] += b.z * w;  acc[7] += b.w * w;
        acc[8] += c.x * w;  acc[9] += c.y * w;  acc[10] += c.z * w; acc[11] += c.w * w;
        acc[12] += d.x * w; acc[13] += d.y * w; acc[14] += d.z * w; acc[15] += d.w * w;
    }

    const float b1j = b1[j];
    const float w2j = w2[j];
    const int lane = tid & 63;
    const int wv = tid >> 6;
#pragma unroll
    for (int e = 0; e < 16; ++e) {
        float v = fmaxf(acc[e] + b1j, 0.f) * w2j;
#pragma unroll
        for (int off = 32; off >= 1; off >>= 1) v += __shfl_xor(v, off);
        if (lane == 0) part[e][wv] = v;
    }
    __syncthreads();
    if (tid < 16) {
        const int eg = e0 + tid;
        if (eg < nEdges) {
            const float x = part[tid][0] + part[tid][1] + part[tid][2] + part[tid][3] + b2[0];
            const float sig = 1.0f / (1.0f + __expf(-x));
            out_w[eg] = sig * evals[eg];
        }
    }
}

extern "C" void kernel_launch(void* const* d_in, const int* in_sizes, int n_in,
                              void* d_out, int out_size, void* d_ws, size_t ws_size,
                              hipStream_t stream)
{
    const float* wave   = (const float*)d_in[0];
    const float* trans  = (const float*)d_in[1];
    const float* target = (const float*)d_in[2];
    const float* w2t    = (const float*)d_in[3];
    const float* t2t    = (const float*)d_in[4];
    const float* temp   = (const float*)d_in[5];
    const float* g_wt   = (const float*)d_in[6];
    const float* g_tt   = (const float*)d_in[7];
    const float* wt_w1  = (const float*)d_in[8];
    const float* wt_b1  = (const float*)d_in[9];
    const float* wt_w2  = (const float*)d_in[10];
    const float* wt_b2  = (const float*)d_in[11];
    const float* tt_w1  = (const float*)d_in[12];
    const float* tt_b1  = (const float*)d_in[13];
    const float* tt_w2  = (const float*)d_in[14];
    const float* tt_b2  = (const float*)d_in[15];

    float* out = (float*)d_out;
    float* wt_src = out;
    float* wt_tgt = out + EW;
    float* wt_wgt = out + 2 * EW;
    float* tt_src = out + 3 * EW;
    float* tt_tgt = out + 3 * EW + ET;
    float* tt_wgt = out + 3 * EW + 2 * ET;

    const size_t nodeFloats = (size_t)(NWAVES + NTRANS + NTRANS + NTGT) * DMODEL;
    const size_t edgeFloats = (size_t)(EW + ET);
    const size_t needBig = (nodeFloats + 2 * edgeFloats) * sizeof(float) + 2 * edgeFloats * sizeof(int);
    const bool bigPath = (ws_size >= needBig);

    float *AW = nullptr, *BW = nullptr, *AT = nullptr, *BT = nullptr;
    float *wt_val, *tt_val; int *wt_idx, *tt_idx;
    if (bigPath) {
        AW = (float*)d_ws;
        BW = AW + NWAVES * DMODEL;
        AT = BW + NTRANS * DMODEL;
        BT = AT + NTRANS * DMODEL;
        wt_val = BT + NTGT * DMODEL;
        tt_val = wt_val + EW;
        wt_idx = (int*)(tt_val + ET);
        tt_idx = wt_idx + EW;
    } else {
        wt_val = (float*)d_ws;
        tt_val = wt_val + EW;
        wt_idx = (int*)(tt_val + ET);
        tt_idx = wt_idx + EW;
    }

    const int nTopk = NWAVES + NTRANS;            // 16384
    const int nGemm = bigPath ? (512 * 3 + 256) : 0;  // 1792
    const int grid = nTopk + nGemm;

    fused_main_kernel<<<grid, 256, 0, stream>>>(
        w2t, g_wt, t2t, g_tt, temp, wave, trans, target, wt_w1, tt_w1,
        wt_src, wt_tgt, wt_idx, wt_val, tt_src, tt_tgt, tt_idx, tt_val,
        AW, BW, AT, BT, nGemm);

    if (bigPath) {
        edge_weight_fused_kernel<<<(EW + ET) / 4, 256, 0, stream>>>(
            AW, BW, AT, BT, wt_idx, wt_val, tt_idx, tt_val,
            wt_b1, wt_w2, wt_b2, tt_b1, tt_w2, tt_b2, wt_wgt, tt_wgt);
    } else {
        edge_mlp_direct_kernel<<<(EW + 15) / 16, 256, 0, stream>>>(wave,  trans,  wt_idx, wt_val, wt_w1, wt_b1, wt_w2, wt_b2, wt_wgt, EW);
        edge_mlp_direct_kernel<<<(ET + 15) / 16, 256, 0, stream>>>(trans, target, tt_idx, tt_val, tt_w1, tt_b1, tt_w2, tt_b2, tt_wgt, ET);
    }
}

// Round 5
// 204.193 us; speedup vs baseline: 1.2439x; 1.0590x over previous
//
#include <hip/hip_runtime.h>

#define NWAVES 8192
#define NTRANS 8192
#define NTGT   4096
#define DMODEL 256
#define TOPK   3
#define EW (NWAVES * TOPK)   // 24576
#define ET (NTRANS * TOPK)   // 24576

struct GemmLds {
    float As[32][68];   // [k][m]; row stride 272B -> float4-aligned
    float Bs[32][64];   // [k][n]
};

// ---------------- per-wave topk body: no barriers, no LDS ----------------
template<int NCOLS>
__device__ __forceinline__ void topk_wave_body(int row, int lane,
        const float* __restrict__ adj, const float* __restrict__ gum, float inv_tau,
        float* __restrict__ out_src, float* __restrict__ out_tgt,
        int* __restrict__ ws_idx, float* __restrict__ ws_val)
{
    constexpr int NIT = NCOLS / 256;   // float4 steps per lane (64 lanes x 4 floats)
    const float4* ap = reinterpret_cast<const float4*>(adj + (size_t)row * NCOLS) + lane;
    const float4* gp = reinterpret_cast<const float4*>(gum + (size_t)row * NCOLS) + lane;
    const int lane4 = lane * 4;

    // dual top-3 trackers (two independent dep chains) + 4 exp-sum accumulators
    float av0 = -1e30f, av1 = -1e30f, av2 = -1e30f; int ai0 = 0, ai1 = 0, ai2 = 0;
    float bv0 = -1e30f, bv1 = -1e30f, bv2 = -1e30f; int bi0 = 0, bi1 = 0, bi2 = 0;
    float s0 = 0.f, s1 = 0.f, s2 = 0.f, s3 = 0.f;

    // scan-insert: strict > (columns ascend per thread -> earliest index wins)
    auto insA = [&](float z, int c) {
        const bool g0 = z > av0, g1 = z > av1, g2 = z > av2;
        av2 = __builtin_amdgcn_fmed3f(z, av1, av2);
        ai2 = g1 ? ai1 : (g2 ? c : ai2);
        av1 = __builtin_amdgcn_fmed3f(z, av0, av1);
        ai1 = g0 ? ai0 : (g1 ? c : ai1);
        av0 = fmaxf(z, av0);
        ai0 = g0 ? c : ai0;
    };
    auto insB = [&](float z, int c) {
        const bool g0 = z > bv0, g1 = z > bv1, g2 = z > bv2;
        bv2 = __builtin_amdgcn_fmed3f(z, bv1, bv2);
        bi2 = g1 ? bi1 : (g2 ? c : bi2);
        bv1 = __builtin_amdgcn_fmed3f(z, bv0, bv1);
        bi1 = g0 ? bi0 : (g1 ? c : bi1);
        bv0 = fmaxf(z, bv0);
        bi0 = g0 ? c : bi0;
    };
    auto proc = [&](const float4& a, const float4& g, int it) {
        const int cb = it * 256 + lane4;
        const float za = fmaf(a.x + g.x, inv_tau, -10.0f);
        const float zb = fmaf(a.y + g.y, inv_tau, -10.0f);
        const float zc = fmaf(a.z + g.z, inv_tau, -10.0f);
        const float zd = fmaf(a.w + g.w, inv_tau, -10.0f);
        s0 += __expf(za); s1 += __expf(zb); s2 += __expf(zc); s3 += __expf(zd);
        insA(za, cb); insA(zb, cb | 1); insB(zc, cb | 2); insB(zd, cb | 3);
    };

    // 4-deep register pipeline: reload each slot right after use
    float4 A0 = ap[0 * 64], A1 = ap[1 * 64], A2 = ap[2 * 64], A3 = ap[3 * 64];
    float4 G0 = gp[0 * 64], G1 = gp[1 * 64], G2 = gp[2 * 64], G3 = gp[3 * 64];
#pragma unroll
    for (int it = 0; it < NIT; it += 4) {
        const bool more = (it + 4) < NIT;
        proc(A0, G0, it + 0);
        if (more) { A0 = ap[(it + 4) * 64]; G0 = gp[(it + 4) * 64]; }
        proc(A1, G1, it + 1);
        if (more) { A1 = ap[(it + 5) * 64]; G1 = gp[(it + 5) * 64]; }
        proc(A2, G2, it + 2);
        if (more) { A2 = ap[(it + 6) * 64]; G2 = gp[(it + 6) * 64]; }
        proc(A3, G3, it + 3);
        if (more) { A3 = ap[(it + 7) * 64]; G3 = gp[(it + 7) * 64]; }
    }

    // index-aware insert (tie -> lower index wins), used for merges only
    auto insIA = [&](float z, int c) {
        const bool e0 = (z == av0), e1 = (z == av1), e2 = (z == av2);
        const bool g0 = (z > av0) || (e0 && c < ai0);
        const bool g1 = (z > av1) || (e1 && c < ai1);
        const bool g2 = (z > av2) || (e2 && c < ai2);
        av2 = __builtin_amdgcn_fmed3f(z, av1, av2);
        ai2 = g1 ? ai1 : (g2 ? c : ai2);
        av1 = __builtin_amdgcn_fmed3f(z, av0, av1);
        ai1 = g0 ? ai0 : (g1 ? c : ai1);
        av0 = fmaxf(z, av0);
        ai0 = g0 ? c : ai0;
    };

    // merge tracker B into A (B held higher column positions per quad -> index-aware)
    insIA(bv0, bi0); insIA(bv1, bi1); insIA(bv2, bi2);
    float s = (s0 + s1) + (s2 + s3);

    // 6-level butterfly across the wave
#pragma unroll
    for (int m = 1; m < 64; m <<= 1) {
        const float u0 = __shfl_xor(av0, m), u1 = __shfl_xor(av1, m), u2 = __shfl_xor(av2, m);
        const int   j0 = __shfl_xor(ai0, m), j1 = __shfl_xor(ai1, m), j2 = __shfl_xor(ai2, m);
        s += __shfl_xor(s, m);
        insIA(u0, j0); insIA(u1, j1); insIA(u2, j2);
    }

    if (lane == 0) {
        const float invS = 1.0f / s;
        const size_t e = (size_t)row * TOPK;
        out_src[e] = (float)row; out_src[e + 1] = (float)row; out_src[e + 2] = (float)row;
        out_tgt[e] = (float)ai0; out_tgt[e + 1] = (float)ai1; out_tgt[e + 2] = (float)ai2;
        ws_idx[e] = ai0; ws_idx[e + 1] = ai1; ws_idx[e + 2] = ai2;
        ws_val[e] = __expf(av0) * invS;
        ws_val[e + 1] = __expf(av1) * invS;
        ws_val[e + 2] = __expf(av2) * invS;
    }
}

// ---------------- gemm body: C[64x64 tile] = A[M,256] @ B[256,256] ----------------
__device__ __forceinline__ void gemm_body(void* ldsraw,
        const float* __restrict__ A, const float* __restrict__ B,
        float* __restrict__ C, int m0, int n0)
{
    GemmLds& L = *reinterpret_cast<GemmLds*>(ldsraw);
    const int tid = threadIdx.x;
    const int tx = tid % 16, ty = tid / 16;
    const int lc = tid % 32;
    const int lr = tid / 32;
    const int bn = tid % 64;
    const int bk = tid / 64;
    float acc[4][4] = {};

    for (int k0 = 0; k0 < DMODEL; k0 += 32) {
#pragma unroll
        for (int i = 0; i < 8; ++i) {
            const int r = lr + i * 8;
            L.As[lc][r] = A[(size_t)(m0 + r) * DMODEL + k0 + lc];
        }
#pragma unroll
        for (int i = 0; i < 8; ++i) {
            const int kk = bk + i * 4;
            L.Bs[kk][bn] = B[(size_t)(k0 + kk) * DMODEL + n0 + bn];
        }
        __syncthreads();
#pragma unroll
        for (int kk = 0; kk < 32; ++kk) {
            const float4 a4 = *reinterpret_cast<const float4*>(&L.As[kk][ty * 4]);
            const float4 b4 = *reinterpret_cast<const float4*>(&L.Bs[kk][tx * 4]);
            const float av[4] = {a4.x, a4.y, a4.z, a4.w};
            const float bv[4] = {b4.x, b4.y, b4.z, b4.w};
#pragma unroll
            for (int i = 0; i < 4; ++i)
#pragma unroll
                for (int j = 0; j < 4; ++j)
                    acc[i][j] += av[i] * bv[j];
        }
        __syncthreads();
    }
#pragma unroll
    for (int i = 0; i < 4; ++i) {
        float4 c4 = {acc[i][0], acc[i][1], acc[i][2], acc[i][3]};
        *reinterpret_cast<float4*>(&C[(size_t)(m0 + ty * 4 + i) * DMODEL + n0 + tx * 4]) = c4;
    }
}

// ---------------- fused main ----------------
__global__ __launch_bounds__(256)
void fused_main_kernel(const float* __restrict__ w2t, const float* __restrict__ g_wt,
                       const float* __restrict__ t2t, const float* __restrict__ g_tt,
                       const float* __restrict__ temp,
                       const float* __restrict__ wave, const float* __restrict__ trans,
                       const float* __restrict__ target,
                       const float* __restrict__ wt_w1, const float* __restrict__ tt_w1,
                       float* wt_src, float* wt_tgt, int* wt_idx, float* wt_val,
                       float* tt_src, float* tt_tgt, int* tt_idx, float* tt_val,
                       float* AW, float* BW, float* AT, float* BT,
                       int nGemm)
{
    __shared__ alignas(16) unsigned char ldsraw[sizeof(GemmLds)];
    const int bid = blockIdx.x;

    int topk_id = -1, gemm_id = -1;
    if (nGemm > 0) {
        const int inter = nGemm * 3;
        if (bid < inter) {
            if (bid % 3 == 0) gemm_id = bid / 3;
            else topk_id = bid - bid / 3 - 1;
        } else {
            topk_id = bid - nGemm;
        }
    } else {
        topk_id = bid;
    }

    if (gemm_id >= 0) {
        const float* A; const float* B; float* C; int mblk, nblk;
        if (gemm_id < 512)       { A = wave;   B = wt_w1;                    C = AW; int g = gemm_id;        mblk = g % 128; nblk = g / 128; }
        else if (gemm_id < 1024) { A = trans;  B = wt_w1 + DMODEL * DMODEL;  C = BW; int g = gemm_id - 512;  mblk = g % 128; nblk = g / 128; }
        else if (gemm_id < 1536) { A = trans;  B = tt_w1;                    C = AT; int g = gemm_id - 1024; mblk = g % 128; nblk = g / 128; }
        else                     { A = target; B = tt_w1 + DMODEL * DMODEL;  C = BT; int g = gemm_id - 1536; mblk = g % 64;  nblk = g / 64;  }
        gemm_body(ldsraw, A, B, C, mblk * 64, nblk * 64);
        return;
    }

    // topk: 4 independent waves per block, one row each; no barriers
    const int lane = threadIdx.x & 63;
    const int wv = threadIdx.x >> 6;
    const int row = topk_id * 4 + wv;
    const float inv_tau = 1.0f / temp[0];
    if (row < NWAVES)
        topk_wave_body<NTRANS>(row, lane, w2t, g_wt, inv_tau, wt_src, wt_tgt, wt_idx, wt_val);
    else
        topk_wave_body<NTGT>(row - NWAVES, lane, t2t, g_tt, inv_tau, tt_src, tt_tgt, tt_idx, tt_val);
}

// ---------------- fused per-edge weight (big path) ----------------
__global__ __launch_bounds__(256)
void edge_weight_fused_kernel(const float* __restrict__ AW, const float* __restrict__ BW,
                              const float* __restrict__ AT, const float* __restrict__ BT,
                              const int* __restrict__ wt_idx, const float* __restrict__ wt_val,
                              const int* __restrict__ tt_idx, const float* __restrict__ tt_val,
                              const float* __restrict__ wt_b1, const float* __restrict__ wt_w2, const float* __restrict__ wt_b2,
                              const float* __restrict__ tt_b1, const float* __restrict__ tt_w2, const float* __restrict__ tt_b2,
                              float* __restrict__ wt_out, float* __restrict__ tt_out)
{
    const int lane = threadIdx.x & 63;
    const int wv   = threadIdx.x >> 6;
    const int eg = blockIdx.x * 4 + wv;

    const bool isWT = (eg < EW);
    const int e = isWT ? eg : eg - EW;
    const float* Arows = isWT ? AW : AT;
    const float* Brows = isWT ? BW : BT;
    const int*   eidx  = isWT ? wt_idx : tt_idx;
    const float* evals = isWT ? wt_val : tt_val;
    const float* b1    = isWT ? wt_b1 : tt_b1;
    const float* w2    = isWT ? wt_w2 : tt_w2;
    const float* b2    = isWT ? wt_b2 : tt_b2;
    float*       outw  = isWT ? wt_out : tt_out;

    const int srow = e / 3;
    const int trow = eidx[e];
    const float4 a4 = *reinterpret_cast<const float4*>(Arows + (size_t)srow * DMODEL + lane * 4);
    const float4 b4 = *reinterpret_cast<const float4*>(Brows + (size_t)trow * DMODEL + lane * 4);
    const float4 c4 = *reinterpret_cast<const float4*>(b1 + lane * 4);
    const float4 w4 = *reinterpret_cast<const float4*>(w2 + lane * 4);
    float acc = fmaxf(a4.x + b4.x + c4.x, 0.f) * w4.x
              + fmaxf(a4.y + b4.y + c4.y, 0.f) * w4.y
              + fmaxf(a4.z + b4.z + c4.z, 0.f) * w4.z
              + fmaxf(a4.w + b4.w + c4.w, 0.f) * w4.w;
#pragma unroll
    for (int off = 32; off >= 1; off >>= 1) acc += __shfl_xor(acc, off);
    if (lane == 0) {
        const float x = acc + b2[0];
        const float sig = 1.0f / (1.0f + __expf(-x));
        outw[e] = sig * evals[e];
    }
}

// ---------------- fallback: direct per-edge MLP (small ws) ----------------
__global__ __launch_bounds__(256)
void edge_mlp_direct_kernel(const float* __restrict__ src_feat,
                            const float* __restrict__ tgt_feat,
                            const int* __restrict__ eidx,
                            const float* __restrict__ evals,
                            const float* __restrict__ w1,
                            const float* __restrict__ b1,
                            const float* __restrict__ w2,
                            const float* __restrict__ b2,
                            float* __restrict__ out_w,
                            int nEdges)
{
    __shared__ float E[512][16];
    __shared__ float part[16][4];
    const int tid = threadIdx.x;
    const int e0 = blockIdx.x * 16;

    for (int i = tid; i < 16 * 128; i += 256) {
        const int e = i >> 7;
        const int q = i & 127;
        const int eg = e0 + e;
        float4 v;
        if (eg < nEdges) {
            if (q < 64) {
                const float* r = src_feat + (size_t)(eg / 3) * DMODEL;
                v = *reinterpret_cast<const float4*>(r + q * 4);
            } else {
                const float* r = tgt_feat + (size_t)eidx[eg] * DMODEL;
                v = *reinterpret_cast<const float4*>(r + (q - 64) * 4);
            }
        } else {
            v = make_float4(0.f, 0.f, 0.f, 0.f);
        }
        const int k = q * 4;
        E[k + 0][e] = v.x; E[k + 1][e] = v.y; E[k + 2][e] = v.z; E[k + 3][e] = v.w;
    }
    __syncthreads();

    const int j = tid;
    float acc[16];
#pragma unroll
    for (int e = 0; e < 16; ++e) acc[e] = 0.f;

    for (int k = 0; k < 512; ++k) {
        const float w = w1[(size_t)k * DMODEL + j];
        const float4 a = *reinterpret_cast<const float4*>(&E[k][0]);
        const float4 b = *reinterpret_cast<const float4*>(&E[k][4]);
        const float4 c = *reinterpret_cast<const float4*>(&E[k][8]);
        const float4 d = *reinterpret_cast<const float4*>(&E[k][12]);
        acc[0] += a.x * w;  acc[1] += a.y * w;  acc[2] += a.z * w;  acc[3] += a.w * w;
        acc[4] += b.x * w;  acc[5] += b.y * w;  acc[6] += b.z * w;  acc[7] += b.w * w;
        acc[8] += c.x * w;  acc[9] += c.y * w;  acc[10] += c.z * w; acc[11] += c.w * w;
        acc[12] += d.x * w; acc[13] += d.y * w; acc[14] += d.z * w; acc[15] += d.w * w;
    }

    const float b1j = b1[j];
    const float w2j = w2[j];
    const int lane = tid & 63;
    const int wv = tid >> 6;
#pragma unroll
    for (int e = 0; e < 16; ++e) {
        float v = fmaxf(acc[e] + b1j, 0.f) * w2j;
#pragma unroll
        for (int off = 32; off >= 1; off >>= 1) v += __shfl_xor(v, off);
        if (lane == 0) part[e][wv] = v;
    }
    __syncthreads();
    if (tid < 16) {
        const int eg = e0 + tid;
        if (eg < nEdges) {
            const float x = part[tid][0] + part[tid][1] + part[tid][2] + part[tid][3] + b2[0];
            const float sig = 1.0f / (1.0f + __expf(-x));
            out_w[eg] = sig * evals[eg];
        }
    }
}

extern "C" void kernel_launch(void* const* d_in, const int* in_sizes, int n_in,
                              void* d_out, int out_size, void* d_ws, size_t ws_size,
                              hipStream_t stream)
{
    const float* wave   = (const float*)d_in[0];
    const float* trans  = (const float*)d_in[1];
    const float* target = (const float*)d_in[2];
    const float* w2t    = (const float*)d_in[3];
    const float* t2t    = (const float*)d_in[4];
    const float* temp   = (const float*)d_in[5];
    const float* g_wt   = (const float*)d_in[6];
    const float* g_tt   = (const float*)d_in[7];
    const float* wt_w1  = (const float*)d_in[8];
    const float* wt_b1  = (const float*)d_in[9];
    const float* wt_w2  = (const float*)d_in[10];
    const float* wt_b2  = (const float*)d_in[11];
    const float* tt_w1  = (const float*)d_in[12];
    const float* tt_b1  = (const float*)d_in[13];
    const float* tt_w2  = (const float*)d_in[14];
    const float* tt_b2  = (const float*)d_in[15];

    float* out = (float*)d_out;
    float* wt_src = out;
    float* wt_tgt = out + EW;
    float* wt_wgt = out + 2 * EW;
    float* tt_src = out + 3 * EW;
    float* tt_tgt = out + 3 * EW + ET;
    float* tt_wgt = out + 3 * EW + 2 * ET;

    const size_t nodeFloats = (size_t)(NWAVES + NTRANS + NTRANS + NTGT) * DMODEL;
    const size_t edgeFloats = (size_t)(EW + ET);
    const size_t needBig = (nodeFloats + 2 * edgeFloats) * sizeof(float) + 2 * edgeFloats * sizeof(int);
    const bool bigPath = (ws_size >= needBig);

    float *AW = nullptr, *BW = nullptr, *AT = nullptr, *BT = nullptr;
    float *wt_val, *tt_val; int *wt_idx, *tt_idx;
    if (bigPath) {
        AW = (float*)d_ws;
        BW = AW + NWAVES * DMODEL;
        AT = BW + NTRANS * DMODEL;
        BT = AT + NTRANS * DMODEL;
        wt_val = BT + NTGT * DMODEL;
        tt_val = wt_val + EW;
        wt_idx = (int*)(tt_val + ET);
        tt_idx = wt_idx + EW;
    } else {
        wt_val = (float*)d_ws;
        tt_val = wt_val + EW;
        wt_idx = (int*)(tt_val + ET);
        tt_idx = wt_idx + EW;
    }

    const int nTopkBlocks = (NWAVES + NTRANS) / 4;        // 4096 (4 rows per block)
    const int nGemm = bigPath ? (512 * 3 + 256) : 0;      // 1792
    const int grid = nTopkBlocks + nGemm;

    fused_main_kernel<<<grid, 256, 0, stream>>>(
        w2t, g_wt, t2t, g_tt, temp, wave, trans, target, wt_w1, tt_w1,
        wt_src, wt_tgt, wt_idx, wt_val, tt_src, tt_tgt, tt_idx, tt_val,
        AW, BW, AT, BT, nGemm);

    if (bigPath) {
        edge_weight_fused_kernel<<<(EW + ET) / 4, 256, 0, stream>>>(
            AW, BW, AT, BT, wt_idx, wt_val, tt_idx, tt_val,
            wt_b1, wt_w2, wt_b2, tt_b1, tt_w2, tt_b2, wt_wgt, tt_wgt);
    } else {
        edge_mlp_direct_kernel<<<(EW + 15) / 16, 256, 0, stream>>>(wave,  trans,  wt_idx, wt_val, wt_w1, wt_b1, wt_w2, wt_b2, wt_wgt, EW);
        edge_mlp_direct_kernel<<<(ET + 15) / 16, 256, 0, stream>>>(trans, target, tt_idx, tt_val, tt_w1, tt_b1, tt_w2, tt_b2, tt_wgt, ET);
    }
}

// Round 6
// 193.093 us; speedup vs baseline: 1.3154x; 1.0575x over previous
//
#include <hip/hip_runtime.h>

#define NWAVES 8192
#define NTRANS 8192
#define NTGT   4096
#define DMODEL 256
#define TOPK   3
#define EW (NWAVES * TOPK)   // 24576
#define ET (NTRANS * TOPK)   // 24576

typedef float vf4 __attribute__((ext_vector_type(4)));

struct GemmLds {
    float As[32][68];   // [k][m]; row stride 272B -> float4-aligned
    float Bs[32][64];   // [k][n]
};

// ---------------- per-wave topk body: no barriers, no LDS, nontemporal stream ----------------
template<int NCOLS>
__device__ __forceinline__ void topk_wave_body(int row, int lane,
        const float* __restrict__ adj, const float* __restrict__ gum, float inv_tau,
        float* __restrict__ out_src, float* __restrict__ out_tgt,
        int* __restrict__ ws_idx, float* __restrict__ ws_val)
{
    constexpr int NIT = NCOLS / 256;   // float4 steps per lane (64 lanes x 4 floats)
    const vf4* ap = reinterpret_cast<const vf4*>(adj + (size_t)row * NCOLS) + lane;
    const vf4* gp = reinterpret_cast<const vf4*>(gum + (size_t)row * NCOLS) + lane;
    const int lane4 = lane * 4;

    // dual top-3 trackers (two independent dep chains) + 4 exp-sum accumulators
    float av0 = -1e30f, av1 = -1e30f, av2 = -1e30f; int ai0 = 0, ai1 = 0, ai2 = 0;
    float bv0 = -1e30f, bv1 = -1e30f, bv2 = -1e30f; int bi0 = 0, bi1 = 0, bi2 = 0;
    float s0 = 0.f, s1 = 0.f, s2 = 0.f, s3 = 0.f;

    // scan-insert: strict > (columns ascend per thread -> earliest index wins)
    auto insA = [&](float z, int c) {
        const bool g0 = z > av0, g1 = z > av1, g2 = z > av2;
        av2 = __builtin_amdgcn_fmed3f(z, av1, av2);
        ai2 = g1 ? ai1 : (g2 ? c : ai2);
        av1 = __builtin_amdgcn_fmed3f(z, av0, av1);
        ai1 = g0 ? ai0 : (g1 ? c : ai1);
        av0 = fmaxf(z, av0);
        ai0 = g0 ? c : ai0;
    };
    auto insB = [&](float z, int c) {
        const bool g0 = z > bv0, g1 = z > bv1, g2 = z > bv2;
        bv2 = __builtin_amdgcn_fmed3f(z, bv1, bv2);
        bi2 = g1 ? bi1 : (g2 ? c : bi2);
        bv1 = __builtin_amdgcn_fmed3f(z, bv0, bv1);
        bi1 = g0 ? bi0 : (g1 ? c : bi1);
        bv0 = fmaxf(z, bv0);
        bi0 = g0 ? c : bi0;
    };
    auto proc = [&](vf4 a, vf4 g, int it) {
        const int cb = it * 256 + lane4;
        const float za = fmaf(a.x + g.x, inv_tau, -10.0f);
        const float zb = fmaf(a.y + g.y, inv_tau, -10.0f);
        const float zc = fmaf(a.z + g.z, inv_tau, -10.0f);
        const float zd = fmaf(a.w + g.w, inv_tau, -10.0f);
        s0 += __expf(za); s1 += __expf(zb); s2 += __expf(zc); s3 += __expf(zd);
        insA(za, cb); insA(zb, cb | 1); insB(zc, cb | 2); insB(zd, cb | 3);
    };

    // 4-deep register pipeline with nontemporal (L1-bypass) loads
    vf4 A0 = __builtin_nontemporal_load(ap + 0 * 64);
    vf4 A1 = __builtin_nontemporal_load(ap + 1 * 64);
    vf4 A2 = __builtin_nontemporal_load(ap + 2 * 64);
    vf4 A3 = __builtin_nontemporal_load(ap + 3 * 64);
    vf4 G0 = __builtin_nontemporal_load(gp + 0 * 64);
    vf4 G1 = __builtin_nontemporal_load(gp + 1 * 64);
    vf4 G2 = __builtin_nontemporal_load(gp + 2 * 64);
    vf4 G3 = __builtin_nontemporal_load(gp + 3 * 64);
#pragma unroll
    for (int it = 0; it < NIT; it += 4) {
        const bool more = (it + 4) < NIT;
        proc(A0, G0, it + 0);
        if (more) { A0 = __builtin_nontemporal_load(ap + (it + 4) * 64); G0 = __builtin_nontemporal_load(gp + (it + 4) * 64); }
        proc(A1, G1, it + 1);
        if (more) { A1 = __builtin_nontemporal_load(ap + (it + 5) * 64); G1 = __builtin_nontemporal_load(gp + (it + 5) * 64); }
        proc(A2, G2, it + 2);
        if (more) { A2 = __builtin_nontemporal_load(ap + (it + 6) * 64); G2 = __builtin_nontemporal_load(gp + (it + 6) * 64); }
        proc(A3, G3, it + 3);
        if (more) { A3 = __builtin_nontemporal_load(ap + (it + 7) * 64); G3 = __builtin_nontemporal_load(gp + (it + 7) * 64); }
    }

    // index-aware insert (tie -> lower index wins), used for merges only
    auto insIA = [&](float z, int c) {
        const bool e0 = (z == av0), e1 = (z == av1), e2 = (z == av2);
        const bool g0 = (z > av0) || (e0 && c < ai0);
        const bool g1 = (z > av1) || (e1 && c < ai1);
        const bool g2 = (z > av2) || (e2 && c < ai2);
        av2 = __builtin_amdgcn_fmed3f(z, av1, av2);
        ai2 = g1 ? ai1 : (g2 ? c : ai2);
        av1 = __builtin_amdgcn_fmed3f(z, av0, av1);
        ai1 = g0 ? ai0 : (g1 ? c : ai1);
        av0 = fmaxf(z, av0);
        ai0 = g0 ? c : ai0;
    };

    // merge tracker B into A (B held higher column positions per quad -> index-aware)
    insIA(bv0, bi0); insIA(bv1, bi1); insIA(bv2, bi2);
    float s = (s0 + s1) + (s2 + s3);

    // 6-level butterfly across the wave
#pragma unroll
    for (int m = 1; m < 64; m <<= 1) {
        const float u0 = __shfl_xor(av0, m), u1 = __shfl_xor(av1, m), u2 = __shfl_xor(av2, m);
        const int   j0 = __shfl_xor(ai0, m), j1 = __shfl_xor(ai1, m), j2 = __shfl_xor(ai2, m);
        s += __shfl_xor(s, m);
        insIA(u0, j0); insIA(u1, j1); insIA(u2, j2);
    }

    if (lane == 0) {
        const float invS = 1.0f / s;
        const size_t e = (size_t)row * TOPK;
        out_src[e] = (float)row; out_src[e + 1] = (float)row; out_src[e + 2] = (float)row;
        out_tgt[e] = (float)ai0; out_tgt[e + 1] = (float)ai1; out_tgt[e + 2] = (float)ai2;
        ws_idx[e] = ai0; ws_idx[e + 1] = ai1; ws_idx[e + 2] = ai2;
        ws_val[e] = __expf(av0) * invS;
        ws_val[e + 1] = __expf(av1) * invS;
        ws_val[e + 2] = __expf(av2) * invS;
    }
}

// ---------------- gemm body: C[64x64 tile] = A[M,256] @ B[256,256] ----------------
__device__ __forceinline__ void gemm_body(void* ldsraw,
        const float* __restrict__ A, const float* __restrict__ B,
        float* __restrict__ C, int m0, int n0)
{
    GemmLds& L = *reinterpret_cast<GemmLds*>(ldsraw);
    const int tid = threadIdx.x;
    const int tx = tid % 16, ty = tid / 16;
    const int lc = tid % 32;
    const int lr = tid / 32;
    const int bn = tid % 64;
    const int bk = tid / 64;
    float acc[4][4] = {};

    for (int k0 = 0; k0 < DMODEL; k0 += 32) {
#pragma unroll
        for (int i = 0; i < 8; ++i) {
            const int r = lr + i * 8;
            L.As[lc][r] = A[(size_t)(m0 + r) * DMODEL + k0 + lc];
        }
#pragma unroll
        for (int i = 0; i < 8; ++i) {
            const int kk = bk + i * 4;
            L.Bs[kk][bn] = B[(size_t)(k0 + kk) * DMODEL + n0 + bn];
        }
        __syncthreads();
#pragma unroll
        for (int kk = 0; kk < 32; ++kk) {
            const float4 a4 = *reinterpret_cast<const float4*>(&L.As[kk][ty * 4]);
            const float4 b4 = *reinterpret_cast<const float4*>(&L.Bs[kk][tx * 4]);
            const float av[4] = {a4.x, a4.y, a4.z, a4.w};
            const float bv[4] = {b4.x, b4.y, b4.z, b4.w};
#pragma unroll
            for (int i = 0; i < 4; ++i)
#pragma unroll
                for (int j = 0; j < 4; ++j)
                    acc[i][j] += av[i] * bv[j];
        }
        __syncthreads();
    }
#pragma unroll
    for (int i = 0; i < 4; ++i) {
        float4 c4 = {acc[i][0], acc[i][1], acc[i][2], acc[i][3]};
        *reinterpret_cast<float4*>(&C[(size_t)(m0 + ty * 4 + i) * DMODEL + n0 + tx * 4]) = c4;
    }
}

// ---------------- fused main ----------------
__global__ __launch_bounds__(256)
void fused_main_kernel(const float* __restrict__ w2t, const float* __restrict__ g_wt,
                       const float* __restrict__ t2t, const float* __restrict__ g_tt,
                       const float* __restrict__ temp,
                       const float* __restrict__ wave, const float* __restrict__ trans,
                       const float* __restrict__ target,
                       const float* __restrict__ wt_w1, const float* __restrict__ tt_w1,
                       float* wt_src, float* wt_tgt, int* wt_idx, float* wt_val,
                       float* tt_src, float* tt_tgt, int* tt_idx, float* tt_val,
                       float* AW, float* BW, float* AT, float* BT,
                       int nGemm)
{
    __shared__ alignas(16) unsigned char ldsraw[sizeof(GemmLds)];
    const int bid = blockIdx.x;

    int topk_id = -1, gemm_id = -1;
    if (nGemm > 0) {
        const int inter = nGemm * 3;
        if (bid < inter) {
            if (bid % 3 == 0) gemm_id = bid / 3;
            else topk_id = bid - bid / 3 - 1;
        } else {
            topk_id = bid - nGemm;
        }
    } else {
        topk_id = bid;
    }

    if (gemm_id >= 0) {
        const float* A; const float* B; float* C; int mblk, nblk;
        if (gemm_id < 512)       { A = wave;   B = wt_w1;                    C = AW; int g = gemm_id;        mblk = g % 128; nblk = g / 128; }
        else if (gemm_id < 1024) { A = trans;  B = wt_w1 + DMODEL * DMODEL;  C = BW; int g = gemm_id - 512;  mblk = g % 128; nblk = g / 128; }
        else if (gemm_id < 1536) { A = trans;  B = tt_w1;                    C = AT; int g = gemm_id - 1024; mblk = g % 128; nblk = g / 128; }
        else                     { A = target; B = tt_w1 + DMODEL * DMODEL;  C = BT; int g = gemm_id - 1536; mblk = g % 64;  nblk = g / 64;  }
        gemm_body(ldsraw, A, B, C, mblk * 64, nblk * 64);
        return;
    }

    // topk: 4 independent waves per block, one row each; no barriers
    const int lane = threadIdx.x & 63;
    const int wv = threadIdx.x >> 6;
    const int row = topk_id * 4 + wv;
    const float inv_tau = 1.0f / temp[0];
    if (row < NWAVES)
        topk_wave_body<NTRANS>(row, lane, w2t, g_wt, inv_tau, wt_src, wt_tgt, wt_idx, wt_val);
    else
        topk_wave_body<NTGT>(row - NWAVES, lane, t2t, g_tt, inv_tau, tt_src, tt_tgt, tt_idx, tt_val);
}

// ---------------- fused per-edge weight (big path) ----------------
__global__ __launch_bounds__(256)
void edge_weight_fused_kernel(const float* __restrict__ AW, const float* __restrict__ BW,
                              const float* __restrict__ AT, const float* __restrict__ BT,
                              const int* __restrict__ wt_idx, const float* __restrict__ wt_val,
                              const int* __restrict__ tt_idx, const float* __restrict__ tt_val,
                              const float* __restrict__ wt_b1, const float* __restrict__ wt_w2, const float* __restrict__ wt_b2,
                              const float* __restrict__ tt_b1, const float* __restrict__ tt_w2, const float* __restrict__ tt_b2,
                              float* __restrict__ wt_out, float* __restrict__ tt_out)
{
    const int lane = threadIdx.x & 63;
    const int wv   = threadIdx.x >> 6;
    const int eg = blockIdx.x * 4 + wv;

    const bool isWT = (eg < EW);
    const int e = isWT ? eg : eg - EW;
    const float* Arows = isWT ? AW : AT;
    const float* Brows = isWT ? BW : BT;
    const int*   eidx  = isWT ? wt_idx : tt_idx;
    const float* evals = isWT ? wt_val : tt_val;
    const float* b1    = isWT ? wt_b1 : tt_b1;
    const float* w2    = isWT ? wt_w2 : tt_w2;
    const float* b2    = isWT ? wt_b2 : tt_b2;
    float*       outw  = isWT ? wt_out : tt_out;

    const int srow = e / 3;
    const int trow = eidx[e];
    const float4 a4 = *reinterpret_cast<const float4*>(Arows + (size_t)srow * DMODEL + lane * 4);
    const float4 b4 = *reinterpret_cast<const float4*>(Brows + (size_t)trow * DMODEL + lane * 4);
    const float4 c4 = *reinterpret_cast<const float4*>(b1 + lane * 4);
    const float4 w4 = *reinterpret_cast<const float4*>(w2 + lane * 4);
    float acc = fmaxf(a4.x + b4.x + c4.x, 0.f) * w4.x
              + fmaxf(a4.y + b4.y + c4.y, 0.f) * w4.y
              + fmaxf(a4.z + b4.z + c4.z, 0.f) * w4.z
              + fmaxf(a4.w + b4.w + c4.w, 0.f) * w4.w;
#pragma unroll
    for (int off = 32; off >= 1; off >>= 1) acc += __shfl_xor(acc, off);
    if (lane == 0) {
        const float x = acc + b2[0];
        const float sig = 1.0f / (1.0f + __expf(-x));
        outw[e] = sig * evals[e];
    }
}

// ---------------- fallback: direct per-edge MLP (small ws) ----------------
__global__ __launch_bounds__(256)
void edge_mlp_direct_kernel(const float* __restrict__ src_feat,
                            const float* __restrict__ tgt_feat,
                            const int* __restrict__ eidx,
                            const float* __restrict__ evals,
                            const float* __restrict__ w1,
                            const float* __restrict__ b1,
                            const float* __restrict__ w2,
                            const float* __restrict__ b2,
                            float* __restrict__ out_w,
                            int nEdges)
{
    __shared__ float E[512][16];
    __shared__ float part[16][4];
    const int tid = threadIdx.x;
    const int e0 = blockIdx.x * 16;

    for (int i = tid; i < 16 * 128; i += 256) {
        const int e = i >> 7;
        const int q = i & 127;
        const int eg = e0 + e;
        float4 v;
        if (eg < nEdges) {
            if (q < 64) {
                const float* r = src_feat + (size_t)(eg / 3) * DMODEL;
                v = *reinterpret_cast<const float4*>(r + q * 4);
            } else {
                const float* r = tgt_feat + (size_t)eidx[eg] * DMODEL;
                v = *reinterpret_cast<const float4*>(r + (q - 64) * 4);
            }
        } else {
            v = make_float4(0.f, 0.f, 0.f, 0.f);
        }
        const int k = q * 4;
        E[k + 0][e] = v.x; E[k + 1][e] = v.y; E[k + 2][e] = v.z; E[k + 3][e] = v.w;
    }
    __syncthreads();

    const int j = tid;
    float acc[16];
#pragma unroll
    for (int e = 0; e < 16; ++e) acc[e] = 0.f;

    for (int k = 0; k < 512; ++k) {
        const float w = w1[(size_t)k * DMODEL + j];
        const float4 a = *reinterpret_cast<const float4*>(&E[k][0]);
        const float4 b = *reinterpret_cast<const float4*>(&E[k][4]);
        const float4 c = *reinterpret_cast<const float4*>(&E[k][8]);
        const float4 d = *reinterpret_cast<const float4*>(&E[k][12]);
        acc[0] += a.x * w;  acc[1] += a.y * w;  acc[2] += a.z * w;  acc[3] += a.w * w;
        acc[4] += b.x * w;  acc[5] += b.y * w;  acc[6] += b.z * w;  acc[7] += b.w * w;
        acc[8] += c.x * w;  acc[9] += c.y * w;  acc[10] += c.z * w; acc[11] += c.w * w;
        acc[12] += d.x * w; acc[13] += d.y * w; acc[14] += d.z * w; acc[15] += d.w * w;
    }

    const float b1j = b1[j];
    const float w2j = w2[j];
    const int lane = tid & 63;
    const int wv = tid >> 6;
#pragma unroll
    for (int e = 0; e < 16; ++e) {
        float v = fmaxf(acc[e] + b1j, 0.f) * w2j;
#pragma unroll
        for (int off = 32; off >= 1; off >>= 1) v += __shfl_xor(v, off);
        if (lane == 0) part[e][wv] = v;
    }
    __syncthreads();
    if (tid < 16) {
        const int eg = e0 + tid;
        if (eg < nEdges) {
            const float x = part[tid][0] + part[tid][1] + part[tid][2] + part[tid][3] + b2[0];
            const float sig = 1.0f / (1.0f + __expf(-x));
            out_w[eg] = sig * evals[eg];
        }
    }
}

extern "C" void kernel_launch(void* const* d_in, const int* in_sizes, int n_in,
                              void* d_out, int out_size, void* d_ws, size_t ws_size,
                              hipStream_t stream)
{
    const float* wave   = (const float*)d_in[0];
    const float* trans  = (const float*)d_in[1];
    const float* target = (const float*)d_in[2];
    const float* w2t    = (const float*)d_in[3];
    const float* t2t    = (const float*)d_in[4];
    const float* temp   = (const float*)d_in[5];
    const float* g_wt   = (const float*)d_in[6];
    const float* g_tt   = (const float*)d_in[7];
    const float* wt_w1  = (const float*)d_in[8];
    const float* wt_b1  = (const float*)d_in[9];
    const float* wt_w2  = (const float*)d_in[10];
    const float* wt_b2  = (const float*)d_in[11];
    const float* tt_w1  = (const float*)d_in[12];
    const float* tt_b1  = (const float*)d_in[13];
    const float* tt_w2  = (const float*)d_in[14];
    const float* tt_b2  = (const float*)d_in[15];

    float* out = (float*)d_out;
    float* wt_src = out;
    float* wt_tgt = out + EW;
    float* wt_wgt = out + 2 * EW;
    float* tt_src = out + 3 * EW;
    float* tt_tgt = out + 3 * EW + ET;
    float* tt_wgt = out + 3 * EW + 2 * ET;

    const size_t nodeFloats = (size_t)(NWAVES + NTRANS + NTRANS + NTGT) * DMODEL;
    const size_t edgeFloats = (size_t)(EW + ET);
    const size_t needBig = (nodeFloats + 2 * edgeFloats) * sizeof(float) + 2 * edgeFloats * sizeof(int);
    const bool bigPath = (ws_size >= needBig);

    float *AW = nullptr, *BW = nullptr, *AT = nullptr, *BT = nullptr;
    float *wt_val, *tt_val; int *wt_idx, *tt_idx;
    if (bigPath) {
        AW = (float*)d_ws;
        BW = AW + NWAVES * DMODEL;
        AT = BW + NTRANS * DMODEL;
        BT = AT + NTRANS * DMODEL;
        wt_val = BT + NTGT * DMODEL;
        tt_val = wt_val + EW;
        wt_idx = (int*)(tt_val + ET);
        tt_idx = wt_idx + EW;
    } else {
        wt_val = (float*)d_ws;
        tt_val = wt_val + EW;
        wt_idx = (int*)(tt_val + ET);
        tt_idx = wt_idx + EW;
    }

    const int nTopkBlocks = (NWAVES + NTRANS) / 4;        // 4096 (4 rows per block)
    const int nGemm = bigPath ? (512 * 3 + 256) : 0;      // 1792
    const int grid = nTopkBlocks + nGemm;

    fused_main_kernel<<<grid, 256, 0, stream>>>(
        w2t, g_wt, t2t, g_tt, temp, wave, trans, target, wt_w1, tt_w1,
        wt_src, wt_tgt, wt_idx, wt_val, tt_src, tt_tgt, tt_idx, tt_val,
        AW, BW, AT, BT, nGemm);

    if (bigPath) {
        edge_weight_fused_kernel<<<(EW + ET) / 4, 256, 0, stream>>>(
            AW, BW, AT, BT, wt_idx, wt_val, tt_idx, tt_val,
            wt_b1, wt_w2, wt_b2, tt_b1, tt_w2, tt_b2, wt_wgt, tt_wgt);
    } else {
        edge_mlp_direct_kernel<<<(EW + 15) / 16, 256, 0, stream>>>(wave,  trans,  wt_idx, wt_val, wt_w1, wt_b1, wt_w2, wt_b2, wt_wgt, EW);
        edge_mlp_direct_kernel<<<(ET + 15) / 16, 256, 0, stream>>>(trans, target, tt_idx, tt_val, tt_w1, tt_b1, tt_w2, tt_b2, tt_wgt, ET);
    }
}